// Round 2
// baseline (329.563 us; speedup 1.0000x reference)
//
#include <hip/hip_runtime.h>

#define IMG_H   128
#define NPIX    (IMG_H * IMG_H)     // 16384
#define TPB     512
#define VITERS  (NPIX / (TPB * 4))  // 8 float4 iterations per thread
#define NWAVES  (TPB / 64)          // 8

// clang-native 4-float vector: required by __builtin_nontemporal_load/store
typedef float vfloat4 __attribute__((ext_vector_type(4)));

// fast atan2, max err ~1e-4 rad (minimax on [0,1] + quadrant fixup)
__device__ __forceinline__ float fast_atan2f(float y, float x) {
    float ax = fabsf(x), ay = fabsf(y);
    float mx = fmaxf(fmaxf(ax, ay), 1e-30f);
    float mn = fminf(ax, ay);
    float a  = mn * __builtin_amdgcn_rcpf(mx);
    float t  = a * a;
    float r  = fmaf(t, fmaf(t, fmaf(t, fmaf(t, 0.0208351f, -0.0851330f),
                                    0.1801410f), -0.3302995f), 0.9998660f);
    r = a * r;
    if (ay > ax)  r = 1.5707963268f - r;
    if (x < 0.0f) r = 3.1415926536f - r;
    return copysignf(r, y);
}

__global__ __launch_bounds__(TPB)
void decode_kernel(const float* __restrict__ W,
                   const float* __restrict__ ng,
                   const float* __restrict__ nu,
                   float* __restrict__ out)
{
    const int b   = blockIdx.x;
    const int tid = threadIdx.x;
    const float* Wb = W + (size_t)b * 16;

    const float w0  = Wb[0],  w1  = Wb[1],  w2  = Wb[2],  w3  = Wb[3];
    const float w4  = Wb[4],  w5  = Wb[5],  w6  = Wb[6],  w7  = Wb[7];
    const float w8  = Wb[8],  w9  = Wb[9],  w10 = Wb[10], w11 = Wb[11];
    const float w12 = Wb[12], w13 = Wb[13], w14 = Wb[14], w15 = Wb[15];

    const float PI    = 3.14159265358979323846f;
    const float PI128 = PI / 128.0f;

    // per-image derived constants
    const float cdisk = w0 * 6.0f;
    const float half  = floorf(fminf(fmaxf(fabsf(w1) * 8.0f + 2.0f, 2.0f), 12.0f));
    const float lo    = 64.0f - half, hi = 64.0f + half;
    const float s2    = w2 * (PI / 64.0f);            // w2*2pi/128
    const float s3    = w3 * (PI / 64.0f);
    const float s4    = w4 * (PI / 256.0f);           // w4*pi*((i+j)/2)/128
    const float c5    = w5 * 10.0f * PI128;           // (fj + w5*10)*pi/128
    const float off7  = truncf(w7 * 5.0f);
    const float bxy   = 64.0f + off7;
    const float sig   = 4.0f + fabsf(w7) * 5.0f;
    const float nb    = -1.0f / (2.0f * sig * sig);   // precise divide
    const float r8    = w8 * 10.0f;
    const float cbs   = floorf(fminf(fmaxf(fabsf(w9) * 8.0f + 2.0f, 2.0f), 16.0f));
    const float icbs  = 1.0f / cbs;                   // precise divide (per-image)
    const float ca    = cosf(w10 * PI);               // precise (threshold constants)
    const float sa    = sinf(w10 * PI);
    const float a11   = w11 * 4.0f;
    const float n12   = 0.2f * w12;
    const float n13   = 0.2f * w13;
    const float con2  = (w15 > 0.0f) ? -(1.0f + w14) : (1.0f + w14);
    const float ccon  = 0.5f - 0.5f * con2;           // (v-0.5)*c+0.5 == v*c + ccon

    // ---- separable tables in LDS -------------------------------------------
    // colA[j] = {c0, cexp, csq, cpar}   colB[j] = {0.5*sin(s4 j), 0.5*cos(s4 j), dy, dy^2}
    // rowA[i] = {dx, dx^2, rowexp, mi}  rowB[i] = {rowpar, rowsin, sin(s4 i), cos(s4 i)}
    __shared__ float4 colA[IMG_H], colB[IMG_H], rowA[IMG_H], rowB[IMG_H];
    __shared__ float  smin[NWAVES], smax[NWAVES];

    if (tid < 128) {
        const float fj  = (float)tid;
        const float dy  = fj - 64.0f;
        const float dyb = fj - bxy;
        // fold: both column-only sins + brightness w6 + the (-0.5*n13) from (u-0.5)*n13
        const float c0 = 0.5f * __sinf(s3 * fj)
                       + 0.5f * __sinf(fmaf(fj, PI128, c5))
                       + w6 - 0.5f * n13;
        const float cexp = __expf(nb * dyb * dyb);
        const float csq  = ((fj >= lo) && (fj < hi)) ? 0.5f : 0.0f;
        // +0.25 bias makes floor exact despite reciprocal rounding (same as before)
        const float cj   = floorf((fj + 0.25f) * icbs);
        const float cpar = (float)(((int)cj) & 1);
        const int   sw   = tid ^ ((tid >> 3) & 7);     // XOR-swizzle: conflict-free b128 reads
        colA[sw] = make_float4(c0, cexp, csq, cpar);
        colB[sw] = make_float4(0.5f * __sinf(s4 * fj), 0.5f * __cosf(s4 * fj), dy, dy * dy);
    } else if (tid < 256) {
        const int   i   = tid - 128;
        const float fi  = (float)i;
        const float dx  = fi - 64.0f;
        const float dxb = fi - bxy;
        const float mi_f = ((fi >= lo) && (fi < hi)) ? 1.0f : 0.0f;
        const float ci   = floorf((fi + 0.25f) * icbs);
        const float rpar = (float)(((int)ci) & 1);
        rowA[i] = make_float4(dx, dx * dx, __expf(nb * dxb * dxb), mi_f);
        rowB[i] = make_float4(rpar, 0.5f * __sinf(s2 * fi), __sinf(s4 * fi), __cosf(s4 * fi));
    }
    __syncthreads();

    const vfloat4* ng4  = (const vfloat4*)(ng  + (size_t)b * NPIX);
    const vfloat4* nu4  = (const vfloat4*)(nu  + (size_t)b * NPIX);
    vfloat4*       out4 = (vfloat4*)(out + (size_t)b * NPIX);

    const int i0 = tid >> 5;            // base row (rows are i0 + 16k)
    const int j0 = (tid & 31) << 2;     // this thread's 4 columns: j0..j0+3 (k-invariant!)

    // hoist all column-dependent values into registers ONCE (same 4 cols for all 8 rows)
    float4 cA[4], cB[4];
    #pragma unroll
    for (int q = 0; q < 4; ++q) {
        const int sw = (j0 + q) ^ ((j0 >> 3) & 7);   // (j0&7)+q <= 7, so >>3 is q-invariant
        cA[q] = colA[sw];
        cB[q] = colB[sw];
    }

    vfloat4 vals[VITERS];
    float vmin =  3.402823466e38f;
    float vmax = -3.402823466e38f;

    // 1-deep prefetch double-buffer for the streaming noise reads
    vfloat4 gc = __builtin_nontemporal_load(ng4 + tid);
    vfloat4 uc = __builtin_nontemporal_load(nu4 + tid);

    #pragma unroll
    for (int k = 0; k < VITERS; ++k) {
        vfloat4 gn = gc, un = uc;
        if (k + 1 < VITERS) {
            gn = __builtin_nontemporal_load(ng4 + (k + 1) * TPB + tid);
            un = __builtin_nontemporal_load(nu4 + (k + 1) * TPB + tid);
        }

        const int    i  = i0 + 16 * k;
        const float4 ra = rowA[i];          // broadcast reads (2 addrs/wave): conflict-free
        const float4 rb = rowB[i];
        const float  dx  = ra.x;
        const float  rr  = ca * dx;         // hoisted half of the rotated-line dot

        const float gg[4] = {gc.x, gc.y, gc.z, gc.w};
        const float uu[4] = {uc.x, uc.y, uc.z, uc.w};

        float vout[4];
        #pragma unroll
        for (int q = 0; q < 4; ++q) {
            const float dy  = cB[q].z;
            const float r2  = ra.y + cB[q].w;          // dx^2 + dy^2: exact (ints < 2^24)
            const float r   = sqrtf(r2);               // correctly rounded: bit-exact vs np

            // disk
            float v = fminf(fmaxf(cdisk - r, 0.0f), 1.0f);
            // column sins + w6 + uniform-noise bias (folded) ; row sin
            v += cA[q].x;
            v += rb.y;
            // central square: row mask * column half-weight
            v = fmaf(ra.w, cA[q].z, v);
            // diagonal sinusoid via angle addition: sin_i*0.5cos_j + cos_i*0.5sin_j
            v = fmaf(rb.z, cB[q].y, v);
            v = fmaf(rb.w, cB[q].x, v);
            // gaussian blob: separable row*col exp
            v = fmaf(ra.z, cA[q].y, v);
            // ring (bit-exact: exact r2, correctly-rounded sqrt)
            const float tr = r - r8;
            if (tr * tr < 10.0f) v += 1.0f;
            // checkerboard: parity(ci) xor parity(cj) == |rpar - cpar|
            v = fmaf(fabsf(rb.x - cA[q].w), 0.3f, v);
            // rotated line
            const float rot = fmaf(sa, dy, rr);
            if (fabsf(rot) < 3.0f) v += 0.6f;
            // angular sinusoid (irreducibly 2-D)
            const float theta = fast_atan2f(dy, dx);
            v = fmaf(0.5f, __sinf(theta * a11), v);
            // noise
            v = fmaf(gg[q], n12, v);
            v = fmaf(uu[q], n13, v);                   // -0.5*n13 folded into cA.x
            // contrast (+ optional inversion folded into con2, offset into ccon)
            v = fmaf(v, con2, ccon);

            vout[q] = v;
            vmin = fminf(vmin, v);
            vmax = fmaxf(vmax, v);
        }
        vfloat4 vv; vv.x = vout[0]; vv.y = vout[1]; vv.z = vout[2]; vv.w = vout[3];
        vals[k] = vv;
        gc = gn; uc = un;
    }

    // wave-level butterfly reduction (64 lanes)
    #pragma unroll
    for (int off = 32; off > 0; off >>= 1) {
        vmin = fminf(vmin, __shfl_xor(vmin, off, 64));
        vmax = fmaxf(vmax, __shfl_xor(vmax, off, 64));
    }

    const int wave = tid >> 6;
    if ((tid & 63) == 0) { smin[wave] = vmin; smax[wave] = vmax; }
    __syncthreads();
    float bmin = smin[0], bmax = smax[0];
    #pragma unroll
    for (int wv = 1; wv < NWAVES; ++wv) {
        bmin = fminf(bmin, smin[wv]);
        bmax = fmaxf(bmax, smax[wv]);
    }

    const float scale = 1.0f / (bmax - bmin + 1e-8f);

    #pragma unroll
    for (int k = 0; k < VITERS; ++k) {
        vfloat4 v = vals[k];
        v.x = (v.x - bmin) * scale;
        v.y = (v.y - bmin) * scale;
        v.z = (v.z - bmin) * scale;
        v.w = (v.w - bmin) * scale;
        __builtin_nontemporal_store(v, out4 + k * TPB + tid);
    }
}

extern "C" void kernel_launch(void* const* d_in, const int* in_sizes, int n_in,
                              void* d_out, int out_size, void* d_ws, size_t ws_size,
                              hipStream_t stream) {
    const float* W  = (const float*)d_in[0];
    const float* ng = (const float*)d_in[1];
    const float* nu = (const float*)d_in[2];
    float* out = (float*)d_out;
    const int B = in_sizes[0] / 16;   // 2048
    decode_kernel<<<dim3(B), dim3(TPB), 0, stream>>>(W, ng, nu, out);
}

// Round 3
// 323.354 us; speedup vs baseline: 1.0192x; 1.0192x over previous
//
#include <hip/hip_runtime.h>

#define IMG_H   128
#define NPIX    (IMG_H * IMG_H)     // 16384
#define TPB     1024
#define VITERS  (NPIX / (TPB * 4))  // 4 float4 iterations per thread
#define NWAVES  (TPB / 64)          // 16

// clang-native 4-float vector: required by __builtin_nontemporal_load/store
typedef float vfloat4 __attribute__((ext_vector_type(4)));

// fast atan2, max err ~1e-4 rad (minimax on [0,1] + quadrant fixup)
__device__ __forceinline__ float fast_atan2f(float y, float x) {
    float ax = fabsf(x), ay = fabsf(y);
    float mx = fmaxf(fmaxf(ax, ay), 1e-30f);
    float mn = fminf(ax, ay);
    float a  = mn * __builtin_amdgcn_rcpf(mx);
    float t  = a * a;
    float r  = fmaf(t, fmaf(t, fmaf(t, fmaf(t, 0.0208351f, -0.0851330f),
                                    0.1801410f), -0.3302995f), 0.9998660f);
    r = a * r;
    if (ay > ax)  r = 1.5707963268f - r;
    if (x < 0.0f) r = 3.1415926536f - r;
    return copysignf(r, y);
}

__global__ __launch_bounds__(TPB)
void decode_kernel(const float* __restrict__ W,
                   const float* __restrict__ ng,
                   const float* __restrict__ nu,
                   float* __restrict__ out)
{
    const int b   = blockIdx.x;
    const int tid = threadIdx.x;
    const float* Wb = W + (size_t)b * 16;

    const float w0  = Wb[0],  w1  = Wb[1],  w2  = Wb[2],  w3  = Wb[3];
    const float w4  = Wb[4],  w5  = Wb[5],  w6  = Wb[6],  w7  = Wb[7];
    const float w8  = Wb[8],  w9  = Wb[9],  w10 = Wb[10], w11 = Wb[11];
    const float w12 = Wb[12], w13 = Wb[13], w14 = Wb[14], w15 = Wb[15];

    const float PI    = 3.14159265358979323846f;
    const float PI128 = PI / 128.0f;

    // per-image derived constants
    const float cdisk = w0 * 6.0f;
    const float half  = floorf(fminf(fmaxf(fabsf(w1) * 8.0f + 2.0f, 2.0f), 12.0f));
    const float lo    = 64.0f - half, hi = 64.0f + half;
    const float s2    = w2 * (PI / 64.0f);            // w2*2pi/128
    const float s3    = w3 * (PI / 64.0f);
    const float s4    = w4 * (PI / 256.0f);           // w4*pi*((i+j)/2)/128
    const float c5    = w5 * 10.0f * PI128;           // (fj + w5*10)*pi/128
    const float off7  = truncf(w7 * 5.0f);
    const float bxy   = 64.0f + off7;
    const float sig   = 4.0f + fabsf(w7) * 5.0f;
    const float nb    = -1.0f / (2.0f * sig * sig);   // precise divide
    const float r8    = w8 * 10.0f;
    const float cbs   = floorf(fminf(fmaxf(fabsf(w9) * 8.0f + 2.0f, 2.0f), 16.0f));
    const float icbs  = 1.0f / cbs;                   // precise divide (per-image)
    const float ca    = cosf(w10 * PI);               // precise (threshold constants)
    const float sa    = sinf(w10 * PI);
    const float a11   = w11 * 4.0f;
    const float n12   = 0.2f * w12;
    const float n13   = 0.2f * w13;
    const float con2  = (w15 > 0.0f) ? -(1.0f + w14) : (1.0f + w14);
    const float ccon  = 0.5f - 0.5f * con2;           // (v-0.5)*c+0.5 == v*c + ccon

    // ---- separable tables in LDS -------------------------------------------
    // colA[j] = {c0, cexp, csq, cpar}   colB[j] = {0.5*sin(s4 j), 0.5*cos(s4 j), dy, dy^2}
    // rowA[i] = {dx, dx^2, rowexp, mi}  rowB[i] = {rowpar, rowsin, sin(s4 i), cos(s4 i)}
    __shared__ float4 colA[IMG_H], colB[IMG_H], rowA[IMG_H], rowB[IMG_H];
    __shared__ float  smin[NWAVES], smax[NWAVES];

    if (tid < 128) {
        const float fj  = (float)tid;
        const float dy  = fj - 64.0f;
        const float dyb = fj - bxy;
        // fold: both column-only sins + brightness w6 + the (-0.5*n13) from (u-0.5)*n13
        const float c0 = 0.5f * __sinf(s3 * fj)
                       + 0.5f * __sinf(fmaf(fj, PI128, c5))
                       + w6 - 0.5f * n13;
        const float cexp = __expf(nb * dyb * dyb);
        const float csq  = ((fj >= lo) && (fj < hi)) ? 0.5f : 0.0f;
        // +0.25 bias makes floor exact despite reciprocal rounding (same as before)
        const float cj   = floorf((fj + 0.25f) * icbs);
        const float cpar = (float)(((int)cj) & 1);
        colA[tid] = make_float4(c0, cexp, csq, cpar);
        colB[tid] = make_float4(0.5f * __sinf(s4 * fj), 0.5f * __cosf(s4 * fj), dy, dy * dy);
    } else if (tid < 256) {
        const int   i   = tid - 128;
        const float fi  = (float)i;
        const float dx  = fi - 64.0f;
        const float dxb = fi - bxy;
        const float mi_f = ((fi >= lo) && (fi < hi)) ? 1.0f : 0.0f;
        const float ci   = floorf((fi + 0.25f) * icbs);
        const float rpar = (float)(((int)ci) & 1);
        rowA[i] = make_float4(dx, dx * dx, __expf(nb * dxb * dxb), mi_f);
        rowB[i] = make_float4(rpar, 0.5f * __sinf(s2 * fi), __sinf(s4 * fi), __cosf(s4 * fi));
    }
    __syncthreads();

    const vfloat4* ng4  = (const vfloat4*)(ng  + (size_t)b * NPIX);
    const vfloat4* nu4  = (const vfloat4*)(nu  + (size_t)b * NPIX);
    vfloat4*       out4 = (vfloat4*)(out + (size_t)b * NPIX);

    const int i0 = tid >> 5;            // base row (rows are i0 + 32k)
    const int j0 = (tid & 31) << 2;     // this thread's 4 columns: j0..j0+3 (k-invariant!)

    // hoist all column-dependent values into registers ONCE (same 4 cols for all 4 rows)
    float4 cA[4], cB[4];
    #pragma unroll
    for (int q = 0; q < 4; ++q) {
        cA[q] = colA[j0 + q];
        cB[q] = colB[j0 + q];
    }

    vfloat4 vals[VITERS];
    float vmin =  3.402823466e38f;
    float vmax = -3.402823466e38f;

    #pragma unroll
    for (int k = 0; k < VITERS; ++k) {
        const int p4 = k * TPB + tid;
        const vfloat4 gc = __builtin_nontemporal_load(ng4 + p4);
        const vfloat4 uc = __builtin_nontemporal_load(nu4 + p4);

        const int    i  = i0 + 32 * k;
        const float4 ra = rowA[i];          // broadcast reads: conflict-free
        const float4 rb = rowB[i];
        const float  dx  = ra.x;
        const float  rr  = ca * dx;         // hoisted half of the rotated-line dot

        const float gg[4] = {gc.x, gc.y, gc.z, gc.w};
        const float uu[4] = {uc.x, uc.y, uc.z, uc.w};

        float vout[4];
        #pragma unroll
        for (int q = 0; q < 4; ++q) {
            const float dy  = cB[q].z;
            const float r2  = ra.y + cB[q].w;          // dx^2 + dy^2: exact (ints < 2^24)
            const float r   = sqrtf(r2);               // correctly rounded: bit-exact vs np

            // disk
            float v = fminf(fmaxf(cdisk - r, 0.0f), 1.0f);
            // column sins + w6 + uniform-noise bias (folded) ; row sin
            v += cA[q].x;
            v += rb.y;
            // central square: row mask * column half-weight
            v = fmaf(ra.w, cA[q].z, v);
            // diagonal sinusoid via angle addition: sin_i*0.5cos_j + cos_i*0.5sin_j
            v = fmaf(rb.z, cB[q].y, v);
            v = fmaf(rb.w, cB[q].x, v);
            // gaussian blob: separable row*col exp
            v = fmaf(ra.z, cA[q].y, v);
            // ring (bit-exact: exact r2, correctly-rounded sqrt)
            const float tr = r - r8;
            if (tr * tr < 10.0f) v += 1.0f;
            // checkerboard: parity(ci) xor parity(cj) == |rpar - cpar|
            v = fmaf(fabsf(rb.x - cA[q].w), 0.3f, v);
            // rotated line
            const float rot = fmaf(sa, dy, rr);
            if (fabsf(rot) < 3.0f) v += 0.6f;
            // angular sinusoid (irreducibly 2-D)
            const float theta = fast_atan2f(dy, dx);
            v = fmaf(0.5f, __sinf(theta * a11), v);
            // noise
            v = fmaf(gg[q], n12, v);
            v = fmaf(uu[q], n13, v);                   // -0.5*n13 folded into cA.x
            // contrast (+ optional inversion folded into con2, offset into ccon)
            v = fmaf(v, con2, ccon);

            vout[q] = v;
            vmin = fminf(vmin, v);
            vmax = fmaxf(vmax, v);
        }
        vfloat4 vv; vv.x = vout[0]; vv.y = vout[1]; vv.z = vout[2]; vv.w = vout[3];
        vals[k] = vv;
    }

    // wave-level butterfly reduction (64 lanes)
    #pragma unroll
    for (int off = 32; off > 0; off >>= 1) {
        vmin = fminf(vmin, __shfl_xor(vmin, off, 64));
        vmax = fmaxf(vmax, __shfl_xor(vmax, off, 64));
    }

    const int wave = tid >> 6;
    if ((tid & 63) == 0) { smin[wave] = vmin; smax[wave] = vmax; }
    __syncthreads();
    float bmin = smin[0], bmax = smax[0];
    #pragma unroll
    for (int wv = 1; wv < NWAVES; ++wv) {
        bmin = fminf(bmin, smin[wv]);
        bmax = fmaxf(bmax, smax[wv]);
    }

    const float scale = 1.0f / (bmax - bmin + 1e-8f);

    #pragma unroll
    for (int k = 0; k < VITERS; ++k) {
        vfloat4 v = vals[k];
        v.x = (v.x - bmin) * scale;
        v.y = (v.y - bmin) * scale;
        v.z = (v.z - bmin) * scale;
        v.w = (v.w - bmin) * scale;
        __builtin_nontemporal_store(v, out4 + k * TPB + tid);
    }
}

extern "C" void kernel_launch(void* const* d_in, const int* in_sizes, int n_in,
                              void* d_out, int out_size, void* d_ws, size_t ws_size,
                              hipStream_t stream) {
    const float* W  = (const float*)d_in[0];
    const float* ng = (const float*)d_in[1];
    const float* nu = (const float*)d_in[2];
    float* out = (float*)d_out;
    const int B = in_sizes[0] / 16;   // 2048
    decode_kernel<<<dim3(B), dim3(TPB), 0, stream>>>(W, ng, nu, out);
}

// Round 4
// 314.119 us; speedup vs baseline: 1.0492x; 1.0294x over previous
//
#include <hip/hip_runtime.h>

#define IMG_H   128
#define NPIX    (IMG_H * IMG_H)     // 16384
#define TPB     1024
#define VITERS  (NPIX / (TPB * 4))  // 4 float4 iterations per thread
#define NWAVES  (TPB / 64)          // 16

// clang-native 4-float vector: required by __builtin_nontemporal_load/store
typedef float vfloat4 __attribute__((ext_vector_type(4)));

// fast atan2, max err ~1e-4 rad (minimax on [0,1] + quadrant fixup)
__device__ __forceinline__ float fast_atan2f(float y, float x) {
    float ax = fabsf(x), ay = fabsf(y);
    float mx = fmaxf(fmaxf(ax, ay), 1e-30f);
    float mn = fminf(ax, ay);
    float a  = mn * __builtin_amdgcn_rcpf(mx);
    float t  = a * a;
    float r  = fmaf(t, fmaf(t, fmaf(t, fmaf(t, 0.0208351f, -0.0851330f),
                                    0.1801410f), -0.3302995f), 0.9998660f);
    r = a * r;
    if (ay > ax)  r = 1.5707963268f - r;
    if (x < 0.0f) r = 3.1415926536f - r;
    return copysignf(r, y);
}

// one-time per launch: theta(i,j) = atan2(j-64, i-64) is W-independent -> table
__global__ __launch_bounds__(256)
void theta_init(float* __restrict__ th) {
    const int p = blockIdx.x * 256 + threadIdx.x;   // grid = NPIX/256
    const int i = p >> 7, j = p & 127;
    th[p] = fast_atan2f((float)j - 64.0f, (float)i - 64.0f);
}

template<bool USE_TAB>
__global__ __launch_bounds__(TPB)
void decode_kernel(const float* __restrict__ W,
                   const float* __restrict__ ng,
                   const float* __restrict__ nu,
                   const float* __restrict__ th,
                   float* __restrict__ out)
{
    const int b   = blockIdx.x;
    const int tid = threadIdx.x;
    const float* Wb = W + (size_t)b * 16;

    const float w0  = Wb[0],  w1  = Wb[1],  w2  = Wb[2],  w3  = Wb[3];
    const float w4  = Wb[4],  w5  = Wb[5],  w6  = Wb[6],  w7  = Wb[7];
    const float w8  = Wb[8],  w9  = Wb[9],  w10 = Wb[10], w11 = Wb[11];
    const float w12 = Wb[12], w13 = Wb[13], w14 = Wb[14], w15 = Wb[15];

    const float PI    = 3.14159265358979323846f;
    const float PI128 = PI / 128.0f;

    // per-image derived constants
    const float cdisk = w0 * 6.0f;
    const float half  = floorf(fminf(fmaxf(fabsf(w1) * 8.0f + 2.0f, 2.0f), 12.0f));
    const float lo    = 64.0f - half, hi = 64.0f + half;
    const float s2    = w2 * (PI / 64.0f);            // w2*2pi/128
    const float s3    = w3 * (PI / 64.0f);
    const float s4    = w4 * (PI / 256.0f);           // w4*pi*((i+j)/2)/128
    const float c5    = w5 * 10.0f * PI128;           // (fj + w5*10)*pi/128
    const float off7  = truncf(w7 * 5.0f);
    const float bxy   = 64.0f + off7;
    const float sig   = 4.0f + fabsf(w7) * 5.0f;
    const float nb    = -1.0f / (2.0f * sig * sig);   // precise divide
    const float r8    = w8 * 10.0f;
    const float cbs   = floorf(fminf(fmaxf(fabsf(w9) * 8.0f + 2.0f, 2.0f), 16.0f));
    const float icbs  = 1.0f / cbs;                   // precise divide (per-image)
    const float ca    = cosf(w10 * PI);               // precise (threshold constants)
    const float sa    = sinf(w10 * PI);
    const float a11   = w11 * 4.0f;
    const float n12   = 0.2f * w12;
    const float n13   = 0.2f * w13;
    const float con2  = (w15 > 0.0f) ? -(1.0f + w14) : (1.0f + w14);
    const float ccon  = 0.5f - 0.5f * con2;           // (v-0.5)*c+0.5 == v*c + ccon

    // ---- separable tables in LDS -------------------------------------------
    // colA[j] = {c0, cexp, csq, cpar}   colB[j] = {0.5*sin(s4 j), 0.5*cos(s4 j), dy, dy^2}
    // rowA[i] = {dx, dx^2, rowexp, mi}  rowB[i] = {rowpar, rowsin, sin(s4 i), cos(s4 i)}
    __shared__ float4 colA[IMG_H], colB[IMG_H], rowA[IMG_H], rowB[IMG_H];
    __shared__ float  smin[NWAVES], smax[NWAVES];

    if (tid < 128) {
        const float fj  = (float)tid;
        const float dy  = fj - 64.0f;
        const float dyb = fj - bxy;
        // fold: both column-only sins + brightness w6 + the (-0.5*n13) from (u-0.5)*n13
        const float c0 = 0.5f * __sinf(s3 * fj)
                       + 0.5f * __sinf(fmaf(fj, PI128, c5))
                       + w6 - 0.5f * n13;
        const float cexp = __expf(nb * dyb * dyb);
        const float csq  = ((fj >= lo) && (fj < hi)) ? 0.5f : 0.0f;
        // +0.25 bias makes floor exact despite reciprocal rounding (same as before)
        const float cj   = floorf((fj + 0.25f) * icbs);
        const float cpar = (float)(((int)cj) & 1);
        const int   sw   = tid ^ ((tid >> 3) & 7);     // XOR-swizzle: spread b128 banks
        colA[sw] = make_float4(c0, cexp, csq, cpar);
        colB[sw] = make_float4(0.5f * __sinf(s4 * fj), 0.5f * __cosf(s4 * fj), dy, dy * dy);
    } else if (tid < 256) {
        const int   i   = tid - 128;
        const float fi  = (float)i;
        const float dx  = fi - 64.0f;
        const float dxb = fi - bxy;
        const float mi_f = ((fi >= lo) && (fi < hi)) ? 1.0f : 0.0f;
        const float ci   = floorf((fi + 0.25f) * icbs);
        const float rpar = (float)(((int)ci) & 1);
        rowA[i] = make_float4(dx, dx * dx, __expf(nb * dxb * dxb), mi_f);
        rowB[i] = make_float4(rpar, 0.5f * __sinf(s2 * fi), __sinf(s4 * fi), __cosf(s4 * fi));
    }
    __syncthreads();

    const vfloat4* ng4  = (const vfloat4*)(ng  + (size_t)b * NPIX);
    const vfloat4* nu4  = (const vfloat4*)(nu  + (size_t)b * NPIX);
    const vfloat4* th4  = (const vfloat4*)th;          // shared across blocks: L2-hot
    vfloat4*       out4 = (vfloat4*)(out + (size_t)b * NPIX);

    const int i0 = tid >> 5;            // base row (rows are i0 + 32k)
    const int j0 = (tid & 31) << 2;     // this thread's 4 columns: j0..j0+3 (k-invariant!)

    // hoist all column-dependent values into registers ONCE (same 4 cols for all 4 rows)
    float4 cA[4], cB[4];
    #pragma unroll
    for (int q = 0; q < 4; ++q) {
        const int sw = (j0 + q) ^ ((j0 >> 3) & 7);   // (j0&7)+q <= 7, so >>3 is q-invariant
        cA[q] = colA[sw];
        cB[q] = colB[sw];
    }

    vfloat4 vals[VITERS];
    float vmin =  3.402823466e38f;
    float vmax = -3.402823466e38f;

    #pragma unroll
    for (int k = 0; k < VITERS; ++k) {
        const int p4 = k * TPB + tid;
        const vfloat4 gc = __builtin_nontemporal_load(ng4 + p4);
        const vfloat4 uc = __builtin_nontemporal_load(nu4 + p4);
        vfloat4 tc;
        if (USE_TAB) tc = th4[p4];                     // plain load: keep L2-cached

        const int    i  = i0 + 32 * k;
        const float4 ra = rowA[i];          // broadcast reads: conflict-free
        const float4 rb = rowB[i];
        const float  dx  = ra.x;
        const float  rr  = ca * dx;         // hoisted half of the rotated-line dot

        const float gg[4] = {gc.x, gc.y, gc.z, gc.w};
        const float uu[4] = {uc.x, uc.y, uc.z, uc.w};

        float vout[4];
        #pragma unroll
        for (int q = 0; q < 4; ++q) {
            const float dy  = cB[q].z;
            const float r2  = ra.y + cB[q].w;          // dx^2 + dy^2: exact (ints < 2^24)
            const float r   = sqrtf(r2);               // correctly rounded: bit-exact vs np

            // disk
            float v = fminf(fmaxf(cdisk - r, 0.0f), 1.0f);
            // column sins + w6 + uniform-noise bias (folded) ; row sin
            v += cA[q].x;
            v += rb.y;
            // central square: row mask * column half-weight
            v = fmaf(ra.w, cA[q].z, v);
            // diagonal sinusoid via angle addition: sin_i*0.5cos_j + cos_i*0.5sin_j
            v = fmaf(rb.z, cB[q].y, v);
            v = fmaf(rb.w, cB[q].x, v);
            // gaussian blob: separable row*col exp
            v = fmaf(ra.z, cA[q].y, v);
            // ring (bit-exact: exact r2, correctly-rounded sqrt)
            const float tr = r - r8;
            if (tr * tr < 10.0f) v += 1.0f;
            // checkerboard: parity(ci) xor parity(cj) == |rpar - cpar|
            v = fmaf(fabsf(rb.x - cA[q].w), 0.3f, v);
            // rotated line
            const float rot = fmaf(sa, dy, rr);
            if (fabsf(rot) < 3.0f) v += 0.6f;
            // angular sinusoid: theta is W-independent -> table (bit-identical fn)
            float theta;
            if (USE_TAB) theta = (q == 0) ? tc.x : (q == 1) ? tc.y : (q == 2) ? tc.z : tc.w;
            else         theta = fast_atan2f(dy, dx);
            v = fmaf(0.5f, __sinf(theta * a11), v);
            // noise
            v = fmaf(gg[q], n12, v);
            v = fmaf(uu[q], n13, v);                   // -0.5*n13 folded into cA.x
            // contrast (+ optional inversion folded into con2, offset into ccon)
            v = fmaf(v, con2, ccon);

            vout[q] = v;
            vmin = fminf(vmin, v);
            vmax = fmaxf(vmax, v);
        }
        vfloat4 vv; vv.x = vout[0]; vv.y = vout[1]; vv.z = vout[2]; vv.w = vout[3];
        vals[k] = vv;
    }

    // wave-level butterfly reduction (64 lanes)
    #pragma unroll
    for (int off = 32; off > 0; off >>= 1) {
        vmin = fminf(vmin, __shfl_xor(vmin, off, 64));
        vmax = fmaxf(vmax, __shfl_xor(vmax, off, 64));
    }

    const int wave = tid >> 6;
    if ((tid & 63) == 0) { smin[wave] = vmin; smax[wave] = vmax; }
    __syncthreads();
    float bmin = smin[0], bmax = smax[0];
    #pragma unroll
    for (int wv = 1; wv < NWAVES; ++wv) {
        bmin = fminf(bmin, smin[wv]);
        bmax = fmaxf(bmax, smax[wv]);
    }

    const float scale = 1.0f / (bmax - bmin + 1e-8f);

    #pragma unroll
    for (int k = 0; k < VITERS; ++k) {
        vfloat4 v = vals[k];
        v.x = (v.x - bmin) * scale;
        v.y = (v.y - bmin) * scale;
        v.z = (v.z - bmin) * scale;
        v.w = (v.w - bmin) * scale;
        __builtin_nontemporal_store(v, out4 + k * TPB + tid);
    }
}

extern "C" void kernel_launch(void* const* d_in, const int* in_sizes, int n_in,
                              void* d_out, int out_size, void* d_ws, size_t ws_size,
                              hipStream_t stream) {
    const float* W  = (const float*)d_in[0];
    const float* ng = (const float*)d_in[1];
    const float* nu = (const float*)d_in[2];
    float* out = (float*)d_out;
    const int B = in_sizes[0] / 16;   // 2048

    if (ws_size >= NPIX * sizeof(float)) {
        float* th = (float*)d_ws;
        theta_init<<<dim3(NPIX / 256), dim3(256), 0, stream>>>(th);
        decode_kernel<true><<<dim3(B), dim3(TPB), 0, stream>>>(W, ng, nu, th, out);
    } else {
        decode_kernel<false><<<dim3(B), dim3(TPB), 0, stream>>>(W, ng, nu, nullptr, out);
    }
}